// Round 1
// 2057.328 us; speedup vs baseline: 1.2394x; 1.2394x over previous
//
#include <hip/hip_runtime.h>
#include <hip/hip_bf16.h>
#include <cstdint>
#include <cstddef>

#define N_NODES 100000
#define N_EDGES 3200000
#define IN_DIM 512
#define HIDDEN 256
#define NUM_CLASSES 1000
#define SCAN_CHUNK 1024

// ---------------- bf16 helpers ----------------

__device__ __forceinline__ float bf2f(unsigned short u) {
  union { unsigned int i; float f; } c; c.i = ((unsigned int)u) << 16; return c.f;
}
__device__ __forceinline__ unsigned short f2bf(float f) {
  union { float f; unsigned int i; } c; c.f = f;
  unsigned int i = c.i;
  unsigned int r = i + 0x7FFFu + ((i >> 16) & 1u);  // round-to-nearest-even
  return (unsigned short)(r >> 16);
}

typedef __attribute__((ext_vector_type(8))) short bf16x8;
typedef __attribute__((ext_vector_type(4))) float f32x4;

// ---------------- CSR build ----------------

__global__ void k_zero_cnt(int* __restrict__ cnt, int n) {
  int i = blockIdx.x * blockDim.x + threadIdx.x;
  if (i < n) cnt[i] = 0;
}

__global__ void k_hist(const int* __restrict__ col, int* __restrict__ cnt, int e) {
  int i = blockIdx.x * blockDim.x + threadIdx.x;
  if (i < e) atomicAdd(&cnt[col[i]], 1);
}

__global__ void k_scan_block_sums(const int* __restrict__ cnt, int* __restrict__ blk, int n) {
  __shared__ int s[256];
  int t = threadIdx.x;
  int base = blockIdx.x * SCAN_CHUNK + t * 4;
  int sum = 0;
#pragma unroll
  for (int k = 0; k < 4; ++k) { int i = base + k; if (i < n) sum += cnt[i]; }
  s[t] = sum; __syncthreads();
  for (int off = 128; off > 0; off >>= 1) {
    if (t < off) s[t] += s[t + off];
    __syncthreads();
  }
  if (t == 0) blk[blockIdx.x] = s[0];
}

// 128 threads; nb <= 128. Exclusive-scans blk in place, writes grand total.
__global__ void k_scan_tops(int* __restrict__ blk, int nb, int* __restrict__ total) {
  __shared__ int s[128];
  int t = threadIdx.x;
  int v = (t < nb) ? blk[t] : 0;
  s[t] = v; __syncthreads();
  for (int off = 1; off < 128; off <<= 1) {
    int x = (t >= off) ? s[t - off] : 0;
    __syncthreads();
    s[t] += x;
    __syncthreads();
  }
  if (t < nb) blk[t] = s[t] - v;     // exclusive block offsets
  if (t == 0) *total = s[127];       // == E (csr_off[N])
}

__global__ void k_scan_final(const int* __restrict__ cnt, const int* __restrict__ blk,
                             int* __restrict__ csr_off, int* __restrict__ cursor,
                             float* __restrict__ dinv, int n) {
  __shared__ int s[256];
  int t = threadIdx.x;
  int base = blockIdx.x * SCAN_CHUNK + t * 4;
  int v[4]; int sum = 0;
#pragma unroll
  for (int k = 0; k < 4; ++k) { int i = base + k; v[k] = (i < n) ? cnt[i] : 0; sum += v[k]; }
  s[t] = sum; __syncthreads();
  for (int off = 1; off < 256; off <<= 1) {
    int x = (t >= off) ? s[t - off] : 0;
    __syncthreads();
    s[t] += x;
    __syncthreads();
  }
  int run = blk[blockIdx.x] + ((t == 0) ? 0 : s[t - 1]);
#pragma unroll
  for (int k = 0; k < 4; ++k) {
    int i = base + k;
    if (i < n) {
      csr_off[i] = run;
      cursor[i] = run;
      dinv[i] = rsqrtf((float)(v[k] + 1));  // deg = incoming edges + self loop
    }
    run += v[k];
  }
}

__global__ void k_fill(const int* __restrict__ row, const int* __restrict__ col,
                       int* __restrict__ cursor, int* __restrict__ csr_row, int e) {
  int i = blockIdx.x * blockDim.x + threadIdx.x;
  if (i < e) {
    int c = col[i];
    int slot = atomicAdd(&cursor[c], 1);
    csr_row[slot] = row[i];
  }
}

// ---------------- hi/lo bf16 split of x ----------------
// Xh = bf16(x), Xl = bf16(x - Xh). Residual ~2^-17 relative.

__global__ void k_split_x(const float4* __restrict__ x, ushort4* __restrict__ xh,
                          ushort4* __restrict__ xl, int n4) {
  int i = blockIdx.x * blockDim.x + threadIdx.x;
  int stride = gridDim.x * blockDim.x;
  for (; i < n4; i += stride) {
    float4 v = x[i];
    ushort4 h, l;
    h.x = f2bf(v.x); l.x = f2bf(v.x - bf2f(h.x));
    h.y = f2bf(v.y); l.y = f2bf(v.y - bf2f(h.y));
    h.z = f2bf(v.z); l.z = f2bf(v.z - bf2f(h.z));
    h.w = f2bf(v.w); l.w = f2bf(v.w - bf2f(h.w));
    xh[i] = h; xl[i] = l;
  }
}

// ---------------- weight prep: fp32 [K][N] -> MFMA-fragment-ready bf16 chunks ----
// Chunk (kb, n) holds B[kb*8+j][n], j=0..7 (8 bf16 = 16B), laid out [kb][Npad][8].
// Writes hi split and lo split; optional duplicate of hi (for the 3-segment layer-1 B).

__global__ void k_prep_w(const float* __restrict__ W, int K, int N, int Npad,
                         unsigned short* __restrict__ hi, unsigned short* __restrict__ lo,
                         unsigned short* __restrict__ hi2) {
  int idx = blockIdx.x * blockDim.x + threadIdx.x;
  int total = (K >> 3) * Npad;
  if (idx >= total) return;
  int kb = idx / Npad, n = idx - kb * Npad;
  unsigned short h8[8], l8[8];
#pragma unroll
  for (int j = 0; j < 8; ++j) {
    float v = (n < N) ? W[(size_t)(kb * 8 + j) * N + n] : 0.f;
    unsigned short h = f2bf(v);
    float r = v - bf2f(h);
    h8[j] = h; l8[j] = f2bf(r);
  }
  size_t off = (size_t)idx * 8;
#pragma unroll
  for (int j = 0; j < 8; ++j) { hi[off + j] = h8[j]; lo[off + j] = l8[j]; }
  if (hi2) {
#pragma unroll
    for (int j = 0; j < 8; ++j) hi2[off + j] = h8[j];
  }
}

// ---------------- MFMA GEMM (bf16 in, fp32 acc) ----------------
// C[m,n] = sum_seg A_seg[m,:] @ B_seg[:,n]   (B pre-packed fragment-ready, concat over segs)
// 128x128 tile, 4 waves (2x2), each wave 64x64 = 4x4 fragments of 16x16x32.
// BK=64. LDS fragment-linear: chunk (kbl, m) at (kbl*128+m)*16B -> contiguous
// 16B/lane fragment reads (conflict-free) AND linear global_load_lds staging.
// Epilogue: optional rowscale (dinv), optional bias, fp32 or bf16 out, masked at M/N edges.

template <bool C_BF16, bool ROW_SCALE, bool ADD_BIAS>
__global__ __launch_bounds__(256, 2) void k_mfma_gemm(
    const unsigned short* __restrict__ A0,
    const unsigned short* __restrict__ A1,
    const unsigned short* __restrict__ A2,
    const unsigned short* __restrict__ Bp,
    const float* __restrict__ rowscale,
    const float* __restrict__ bias,
    void* __restrict__ Cv,
    int M, int N, int Npad, int Kseg, int nseg) {
  __shared__ __align__(16) unsigned short As[1024 * 8];  // 16 KB
  __shared__ __align__(16) unsigned short Bs[1024 * 8];  // 16 KB
  const int tid = threadIdx.x;
  const int wid = tid >> 6, lane = tid & 63;
  const int lr = lane & 15, lk = lane >> 4;
  const int m0 = blockIdx.y * 128, n0 = blockIdx.x * 128;
  const int m0w = (wid >> 1) * 64, n0w = (wid & 1) * 64;

  f32x4 acc[4][4] = {};

  const int KTOT = Kseg * nseg;
  int seg = 0, kin = 0;
  for (int kt = 0; kt < KTOT; kt += 64) {
    const unsigned short* Aseg = (seg == 0) ? A0 : ((seg == 1) ? A1 : A2);
    // ---- stage A tile: chunks c = kbl*128 + m, each 16B ----
#pragma unroll
    for (int r = 0; r < 4; ++r) {
      int c = r * 256 + tid;
      int kbl = c >> 7, m = c & 127;
      int gm = m0 + m; if (gm > M - 1) gm = M - 1;   // clamp (masked at store)
      const unsigned short* src = Aseg + (size_t)gm * Kseg + (kin + kbl * 8);
      unsigned short* dst = &As[(size_t)(r * 256 + (wid << 6)) * 8];  // wave-uniform base
      __builtin_amdgcn_global_load_lds(
          (const __attribute__((address_space(1))) unsigned int*)src,
          (__attribute__((address_space(3))) unsigned int*)dst, 16, 0, 0);
    }
    // ---- stage B tile: chunks c = kbl*128 + n ----
    const int kb0 = kt >> 3;
#pragma unroll
    for (int r = 0; r < 4; ++r) {
      int c = r * 256 + tid;
      int kbl = c >> 7, n = c & 127;
      const unsigned short* src = Bp + ((size_t)(kb0 + kbl) * Npad + (n0 + n)) * 8;
      unsigned short* dst = &Bs[(size_t)(r * 256 + (wid << 6)) * 8];
      __builtin_amdgcn_global_load_lds(
          (const __attribute__((address_space(1))) unsigned int*)src,
          (__attribute__((address_space(3))) unsigned int*)dst, 16, 0, 0);
    }
    __syncthreads();   // drains vmcnt before barrier (compiler-inserted)
    // ---- compute: 2 x (16 MFMA) per wave ----
#pragma unroll
    for (int kh = 0; kh < 2; ++kh) {
      bf16x8 bfr[4];
#pragma unroll
      for (int nf = 0; nf < 4; ++nf)
        bfr[nf] = *(const bf16x8*)&Bs[(size_t)((((kh * 4 + lk) << 7) + n0w + nf * 16 + lr)) * 8];
#pragma unroll
      for (int mf = 0; mf < 4; ++mf) {
        bf16x8 af = *(const bf16x8*)&As[(size_t)((((kh * 4 + lk) << 7) + m0w + mf * 16 + lr)) * 8];
#pragma unroll
        for (int nf = 0; nf < 4; ++nf)
          acc[mf][nf] = __builtin_amdgcn_mfma_f32_16x16x32_bf16(af, bfr[nf], acc[mf][nf], 0, 0, 0);
      }
    }
    __syncthreads();
    kin += 64;
    if (kin == Kseg) { kin = 0; ++seg; }
  }

  // ---- epilogue: D layout col=lane&15, row=(lane>>4)*4+reg  [verified m89] ----
  const int orow = lk * 4;
#pragma unroll
  for (int mf = 0; mf < 4; ++mf) {
#pragma unroll
    for (int i = 0; i < 4; ++i) {
      int gm = m0 + m0w + mf * 16 + orow + i;
      if (gm >= M) continue;
      float rs = ROW_SCALE ? rowscale[gm] : 1.0f;
#pragma unroll
      for (int nf = 0; nf < 4; ++nf) {
        int gn = n0 + n0w + nf * 16 + lr;
        if (gn >= N) continue;
        float o = acc[mf][nf][i] * rs;
        if (ADD_BIAS) o += bias[gn];
        if constexpr (C_BF16) {
          ((unsigned short*)Cv)[(size_t)gm * N + gn] = f2bf(o);
        } else {
          ((float*)Cv)[(size_t)gm * N + gn] = o;
        }
      }
    }
  }
}

// ---------------- Aggregation: one wave per node, 4 bf16 channels per lane ----------------
// out[c] = bf16( relu(dinv[c] * (sum_{e: col=c} Hs[row_e] + Hs[c]) + bias) )
// Hs already carries the dinv[row] factor (fused into GEMM epilogue). fp32 accumulate.

__global__ __launch_bounds__(256) void k_agg_bias_relu(
    const ushort4* __restrict__ Hs, const int* __restrict__ csr_off,
    const int* __restrict__ csr_row, const float* __restrict__ dinv,
    const float* __restrict__ bias, ushort4* __restrict__ out, int n) {
  int node = blockIdx.x * 4 + (threadIdx.x >> 6);
  if (node >= n) return;
  int lane = threadIdx.x & 63;                 // HIDDEN/4 = 64 lanes x 4 channels
  ushort4 sv = Hs[(size_t)node * 64 + lane];   // self loop
  float ax = bf2f(sv.x), ay = bf2f(sv.y), az = bf2f(sv.z), aw = bf2f(sv.w);
  int beg = csr_off[node], end = csr_off[node + 1];
  for (int j = beg; j < end; ++j) {
    int r = csr_row[j];
    ushort4 v = Hs[(size_t)r * 64 + lane];
    ax += bf2f(v.x); ay += bf2f(v.y); az += bf2f(v.z); aw += bf2f(v.w);
  }
  float di = dinv[node];
  float4 b = ((const float4*)bias)[lane];
  ushort4 o;
  o.x = f2bf(fmaxf(fmaf(ax, di, b.x), 0.f));
  o.y = f2bf(fmaxf(fmaf(ay, di, b.y), 0.f));
  o.z = f2bf(fmaxf(fmaf(az, di, b.z), 0.f));
  o.w = f2bf(fmaxf(fmaf(aw, di, b.w), 0.f));
  out[(size_t)node * 64 + lane] = o;
}

// ---------------- launch ----------------

extern "C" void kernel_launch(void* const* d_in, const int* in_sizes, int n_in,
                              void* d_out, int out_size, void* d_ws, size_t ws_size,
                              hipStream_t stream) {
  const float* x   = (const float*)d_in[0];
  const int*   ei  = (const int*)d_in[1];   // int32! (JAX x64 disabled; harness: integer -> int*)
  const float* W1  = (const float*)d_in[2];
  const float* b1  = (const float*)d_in[3];
  const float* W2  = (const float*)d_in[4];
  const float* b2  = (const float*)d_in[5];
  const float* Wfc = (const float*)d_in[6];
  const float* bfc = (const float*)d_in[7];
  float* out = (float*)d_out;

  const int* row = ei;             // sources
  const int* col = ei + N_EDGES;   // targets

  // Scratch carved from d_out (400 MB fp32; all regions dead before FC writes):
  //   bufA (pre-agg Hs, bf16, 51.2 MB) | csr_row (12.8 MB) | Xh (102.4) | Xl (102.4)
  //   | Bp1 (0.79 MB) | Bp2 (0.26 MB)
  char* q = (char*)d_out;
  unsigned short* bufA    = (unsigned short*)q;                        // [N*HIDDEN] bf16
  int*            csr_row = (int*)(q + 51200000);
  unsigned short* Xh      = (unsigned short*)(q + 64000000);           // [N][512] bf16
  unsigned short* Xl      = (unsigned short*)(q + 166400000);
  unsigned short* Bp1     = (unsigned short*)(q + 268800000);          // 3 segs x 64kb x 256 x 8
  unsigned short* Bp2     = (unsigned short*)(q + 269600000);          // 2 segs x 32kb x 256 x 8

  // d_ws: small CSR arrays + post-agg feature buffer + FC weights (must survive into FC)
  char* p = (char*)d_ws;
  auto alloc = [&](size_t bytes) { char* r = p; p += (bytes + 255) & ~(size_t)255; return r; };
  int*   cnt     = (int*)alloc(sizeof(int) * N_NODES);
  int*   csr_off = (int*)alloc(sizeof(int) * (N_NODES + 1));
  int*   cursor  = (int*)alloc(sizeof(int) * N_NODES);
  int*   blk     = (int*)alloc(sizeof(int) * 128);
  float* dinv    = (float*)alloc(sizeof(float) * N_NODES);
  unsigned short* bufB = (unsigned short*)alloc(sizeof(unsigned short) * (size_t)N_NODES * HIDDEN);
  unsigned short* BpFC = (unsigned short*)alloc(sizeof(unsigned short) * (size_t)2 * 32 * 1024 * 8); // 1 MB

  const int nscan = (N_NODES + SCAN_CHUNK - 1) / SCAN_CHUNK;  // 98 (<=128)

  // input prep (independent of CSR chain)
  hipLaunchKernelGGL(k_split_x, dim3(2048), dim3(256), 0, stream,
                     (const float4*)x, (ushort4*)Xh, (ushort4*)Xl, N_NODES * IN_DIM / 4);
  // W1: segs [hi | lo | hi], 64 kb-rows per seg, Npad=256
  hipLaunchKernelGGL(k_prep_w, dim3((64 * 256 + 255) / 256), dim3(256), 0, stream,
                     W1, IN_DIM, HIDDEN, HIDDEN, Bp1, Bp1 + (size_t)64 * 256 * 8,
                     Bp1 + (size_t)2 * 64 * 256 * 8);
  // W2: segs [hi | lo], 32 kb-rows per seg
  hipLaunchKernelGGL(k_prep_w, dim3((32 * 256 + 255) / 256), dim3(256), 0, stream,
                     W2, HIDDEN, HIDDEN, HIDDEN, Bp2, Bp2 + (size_t)32 * 256 * 8,
                     (unsigned short*)nullptr);
  // Wfc: segs [hi | lo], Npad=1024
  hipLaunchKernelGGL(k_prep_w, dim3((32 * 1024 + 255) / 256), dim3(256), 0, stream,
                     Wfc, HIDDEN, NUM_CLASSES, 1024, BpFC, BpFC + (size_t)32 * 1024 * 8,
                     (unsigned short*)nullptr);

  // CSR build
  hipLaunchKernelGGL(k_zero_cnt, dim3((N_NODES + 255) / 256), dim3(256), 0, stream, cnt, N_NODES);
  hipLaunchKernelGGL(k_hist, dim3((N_EDGES + 255) / 256), dim3(256), 0, stream, col, cnt, N_EDGES);
  hipLaunchKernelGGL(k_scan_block_sums, dim3(nscan), dim3(256), 0, stream, cnt, blk, N_NODES);
  hipLaunchKernelGGL(k_scan_tops, dim3(1), dim3(128), 0, stream, blk, nscan, csr_off + N_NODES);
  hipLaunchKernelGGL(k_scan_final, dim3(nscan), dim3(256), 0, stream, cnt, blk, csr_off, cursor, dinv, N_NODES);
  hipLaunchKernelGGL(k_fill, dim3((N_EDGES + 255) / 256), dim3(256), 0, stream, row, col, cursor, csr_row, N_EDGES);

  const int MB = (N_NODES + 127) / 128;  // 782

  // Layer 1: Hs = bf16((x @ W1) * dinv[row]); x@W1 = Xh@W1h + Xh@W1l + Xl@W1h
  hipLaunchKernelGGL((k_mfma_gemm<true, true, false>), dim3(HIDDEN / 128, MB), dim3(256), 0, stream,
                     Xh, Xh, Xl, Bp1, dinv, (const float*)nullptr, bufA,
                     N_NODES, HIDDEN, HIDDEN, IN_DIM, 3);
  hipLaunchKernelGGL(k_agg_bias_relu, dim3((N_NODES + 3) / 4), dim3(256), 0, stream,
                     (const ushort4*)bufA, csr_off, csr_row, dinv, b1, (ushort4*)bufB, N_NODES);

  // Layer 2: A (bufB) is exact bf16; B split hi+lo
  hipLaunchKernelGGL((k_mfma_gemm<true, true, false>), dim3(HIDDEN / 128, MB), dim3(256), 0, stream,
                     bufB, bufB, bufB, Bp2, dinv, (const float*)nullptr, bufA,
                     N_NODES, HIDDEN, HIDDEN, HIDDEN, 2);
  hipLaunchKernelGGL(k_agg_bias_relu, dim3((N_NODES + 3) / 4), dim3(256), 0, stream,
                     (const ushort4*)bufA, csr_off, csr_row, dinv, b2, (ushort4*)bufB, N_NODES);

  // FC: out = bufB @ Wfc + bfc (fp32 out over the whole d_out; scratch regions dead by now)
  hipLaunchKernelGGL((k_mfma_gemm<false, false, true>), dim3(1024 / 128, MB), dim3(256), 0, stream,
                     bufB, bufB, bufB, BpFC, (const float*)nullptr, bfc, out,
                     N_NODES, NUM_CLASSES, 1024, HIDDEN, 2);
}

// Round 2
// 1782.993 us; speedup vs baseline: 1.4301x; 1.1539x over previous
//
#include <hip/hip_runtime.h>
#include <hip/hip_bf16.h>
#include <cstdint>
#include <cstddef>

#define N_NODES 100000
#define N_EDGES 3200000
#define IN_DIM 512
#define HIDDEN 256
#define NUM_CLASSES 1000
#define SCAN_CHUNK 1024

// ---------------- bf16 helpers ----------------

__device__ __forceinline__ float bf2f(unsigned short u) {
  union { unsigned int i; float f; } c; c.i = ((unsigned int)u) << 16; return c.f;
}
__device__ __forceinline__ unsigned short f2bf(float f) {
  union { float f; unsigned int i; } c; c.f = f;
  unsigned int i = c.i;
  unsigned int r = i + 0x7FFFu + ((i >> 16) & 1u);  // round-to-nearest-even
  return (unsigned short)(r >> 16);
}

typedef __attribute__((ext_vector_type(8))) short bf16x8;
typedef __attribute__((ext_vector_type(4))) float f32x4;

// ---------------- CSR build ----------------

__global__ void k_zero_cnt(int* __restrict__ cnt, int n) {
  int i = blockIdx.x * blockDim.x + threadIdx.x;
  if (i < n) cnt[i] = 0;
}

__global__ void k_hist(const int* __restrict__ col, int* __restrict__ cnt, int e) {
  int i = blockIdx.x * blockDim.x + threadIdx.x;
  if (i < e) atomicAdd(&cnt[col[i]], 1);
}

__global__ void k_scan_block_sums(const int* __restrict__ cnt, int* __restrict__ blk, int n) {
  __shared__ int s[256];
  int t = threadIdx.x;
  int base = blockIdx.x * SCAN_CHUNK + t * 4;
  int sum = 0;
#pragma unroll
  for (int k = 0; k < 4; ++k) { int i = base + k; if (i < n) sum += cnt[i]; }
  s[t] = sum; __syncthreads();
  for (int off = 128; off > 0; off >>= 1) {
    if (t < off) s[t] += s[t + off];
    __syncthreads();
  }
  if (t == 0) blk[blockIdx.x] = s[0];
}

// 128 threads; nb <= 128. Exclusive-scans blk in place, writes grand total.
__global__ void k_scan_tops(int* __restrict__ blk, int nb, int* __restrict__ total) {
  __shared__ int s[128];
  int t = threadIdx.x;
  int v = (t < nb) ? blk[t] : 0;
  s[t] = v; __syncthreads();
  for (int off = 1; off < 128; off <<= 1) {
    int x = (t >= off) ? s[t - off] : 0;
    __syncthreads();
    s[t] += x;
    __syncthreads();
  }
  if (t < nb) blk[t] = s[t] - v;     // exclusive block offsets
  if (t == 0) *total = s[127];       // == E (csr_off[N])
}

__global__ void k_scan_final(const int* __restrict__ cnt, const int* __restrict__ blk,
                             int* __restrict__ csr_off, int* __restrict__ cursor,
                             float* __restrict__ dinv, int n) {
  __shared__ int s[256];
  int t = threadIdx.x;
  int base = blockIdx.x * SCAN_CHUNK + t * 4;
  int v[4]; int sum = 0;
#pragma unroll
  for (int k = 0; k < 4; ++k) { int i = base + k; v[k] = (i < n) ? cnt[i] : 0; sum += v[k]; }
  s[t] = sum; __syncthreads();
  for (int off = 1; off < 256; off <<= 1) {
    int x = (t >= off) ? s[t - off] : 0;
    __syncthreads();
    s[t] += x;
    __syncthreads();
  }
  int run = blk[blockIdx.x] + ((t == 0) ? 0 : s[t - 1]);
#pragma unroll
  for (int k = 0; k < 4; ++k) {
    int i = base + k;
    if (i < n) {
      csr_off[i] = run;
      cursor[i] = run;
      dinv[i] = rsqrtf((float)(v[k] + 1));  // deg = incoming edges + self loop
    }
    run += v[k];
  }
}

__global__ void k_fill(const int* __restrict__ row, const int* __restrict__ col,
                       int* __restrict__ cursor, int* __restrict__ csr_row, int e) {
  int i = blockIdx.x * blockDim.x + threadIdx.x;
  if (i < e) {
    int c = col[i];
    int slot = atomicAdd(&cursor[c], 1);
    csr_row[slot] = row[i];
  }
}

// ---------------- hi/lo bf16 split of x ----------------
// Xh = bf16(x), Xl = bf16(x - Xh). Residual ~2^-17 relative.

__global__ void k_split_x(const float4* __restrict__ x, ushort4* __restrict__ xh,
                          ushort4* __restrict__ xl, int n4) {
  int i = blockIdx.x * blockDim.x + threadIdx.x;
  int stride = gridDim.x * blockDim.x;
  for (; i < n4; i += stride) {
    float4 v = x[i];
    ushort4 h, l;
    h.x = f2bf(v.x); l.x = f2bf(v.x - bf2f(h.x));
    h.y = f2bf(v.y); l.y = f2bf(v.y - bf2f(h.y));
    h.z = f2bf(v.z); l.z = f2bf(v.z - bf2f(h.z));
    h.w = f2bf(v.w); l.w = f2bf(v.w - bf2f(h.w));
    xh[i] = h; xl[i] = l;
  }
}

// ---------------- weight prep: fp32 [K][N] -> MFMA-fragment-ready bf16 chunks ----
// Chunk (kb, n) holds B[kb*8+j][n], j=0..7 (8 bf16 = 16B), laid out [kb][Npad][8].
// Writes hi split and lo split; optional duplicate of hi (for the 3-segment layer-1 B).

__global__ void k_prep_w(const float* __restrict__ W, int K, int N, int Npad,
                         unsigned short* __restrict__ hi, unsigned short* __restrict__ lo,
                         unsigned short* __restrict__ hi2) {
  int idx = blockIdx.x * blockDim.x + threadIdx.x;
  int total = (K >> 3) * Npad;
  if (idx >= total) return;
  int kb = idx / Npad, n = idx - kb * Npad;
  unsigned short h8[8], l8[8];
#pragma unroll
  for (int j = 0; j < 8; ++j) {
    float v = (n < N) ? W[(size_t)(kb * 8 + j) * N + n] : 0.f;
    unsigned short h = f2bf(v);
    float r = v - bf2f(h);
    h8[j] = h; l8[j] = f2bf(r);
  }
  size_t off = (size_t)idx * 8;
#pragma unroll
  for (int j = 0; j < 8; ++j) { hi[off + j] = h8[j]; lo[off + j] = l8[j]; }
  if (hi2) {
#pragma unroll
    for (int j = 0; j < 8; ++j) hi2[off + j] = h8[j];
  }
}

// ---------------- MFMA GEMM (bf16 in, fp32 acc) ----------------
// C = sum over (A-source, its B-segs) of A_src @ B_seg. Up to 2 A sources
// (each staged ONCE per K-tile), up to 2 B segments per source (both staged
// alongside; 2x MFMA per barrier pair). B pre-packed fragment-ready:
// [seg][Kseg/8][Npad][8]. 128x128 tile, 4 waves 2x2, 16x16x32 MFMA, BK=64.
// LDS fragment-linear: chunk (kbl, m) at (kbl*128+m)*16B -> contiguous 16B/lane
// fragment reads (conflict-free) AND linear global_load_lds staging.

template <bool C_BF16, bool ROW_SCALE, bool ADD_BIAS>
__global__ __launch_bounds__(256, 3) void k_mfma_gemm(
    const unsigned short* __restrict__ A0, int nb0,
    const unsigned short* __restrict__ A1, int nb1,
    const unsigned short* __restrict__ Bp,
    const float* __restrict__ rowscale,
    const float* __restrict__ bias,
    void* __restrict__ Cv,
    int M, int N, int Npad, int Kseg) {
  __shared__ __align__(16) unsigned short As[1024 * 8];  // 16 KB: one 128x64 A tile
  __shared__ __align__(16) unsigned short Bs[2048 * 8];  // 32 KB: up to two B seg tiles
  const int tid = threadIdx.x;
  const int wid = tid >> 6, lane = tid & 63;
  const int lr = lane & 15, lk = lane >> 4;
  const int m0 = blockIdx.y * 128, n0 = blockIdx.x * 128;
  const int m0w = (wid >> 1) * 64, n0w = (wid & 1) * 64;

  f32x4 acc[4][4] = {};
  const int kbseg = Kseg >> 3;

  int segbase = 0;
  for (int src = 0; src < 2; ++src) {
    const int nb = (src == 0) ? nb0 : nb1;
    if (nb == 0) continue;
    const unsigned short* A = (src == 0) ? A0 : A1;
    for (int kt = 0; kt < Kseg; kt += 64) {
      // ---- stage A tile once: chunks c = kbl*128 + m, each 16B ----
#pragma unroll
      for (int r = 0; r < 4; ++r) {
        int c = r * 256 + tid;
        int kbl = c >> 7, m = c & 127;
        int gm = m0 + m; if (gm > M - 1) gm = M - 1;   // clamp (masked at store)
        const unsigned short* srcp = A + (size_t)gm * Kseg + (kt + kbl * 8);
        unsigned short* dst = &As[(size_t)(r * 256 + (wid << 6)) * 8];  // wave-uniform base
        __builtin_amdgcn_global_load_lds(
            (const __attribute__((address_space(1))) unsigned int*)srcp,
            (__attribute__((address_space(3))) unsigned int*)dst, 16, 0, 0);
      }
      // ---- stage B tiles for all segs of this source ----
      const int kb0 = kt >> 3;
      for (int s = 0; s < nb; ++s) {
#pragma unroll
        for (int r = 0; r < 4; ++r) {
          int c = r * 256 + tid;
          int kbl = c >> 7, n = c & 127;
          const unsigned short* srcp =
              Bp + ((size_t)((segbase + s) * kbseg + kb0 + kbl) * Npad + (n0 + n)) * 8;
          unsigned short* dst = &Bs[(size_t)(s * 1024 + r * 256 + (wid << 6)) * 8];
          __builtin_amdgcn_global_load_lds(
              (const __attribute__((address_space(1))) unsigned int*)srcp,
              (__attribute__((address_space(3))) unsigned int*)dst, 16, 0, 0);
        }
      }
      __syncthreads();   // drains vmcnt before barrier (compiler-inserted)
      // ---- compute: per seg, 2 x (16 MFMA) per wave, same A fragments ----
      for (int s = 0; s < nb; ++s) {
#pragma unroll
        for (int kh = 0; kh < 2; ++kh) {
          bf16x8 bfr[4];
#pragma unroll
          for (int nf = 0; nf < 4; ++nf)
            bfr[nf] = *(const bf16x8*)&Bs[(size_t)(s * 1024 + (((kh * 4 + lk) << 7) + n0w + nf * 16 + lr)) * 8];
#pragma unroll
          for (int mf = 0; mf < 4; ++mf) {
            bf16x8 af = *(const bf16x8*)&As[(size_t)((((kh * 4 + lk) << 7) + m0w + mf * 16 + lr)) * 8];
#pragma unroll
            for (int nf = 0; nf < 4; ++nf)
              acc[mf][nf] = __builtin_amdgcn_mfma_f32_16x16x32_bf16(af, bfr[nf], acc[mf][nf], 0, 0, 0);
          }
        }
      }
      __syncthreads();
    }
    segbase += nb;
  }

  // ---- epilogue: D layout col=lane&15, row=(lane>>4)*4+reg  [verified m89] ----
  const int orow = lk * 4;
#pragma unroll
  for (int mf = 0; mf < 4; ++mf) {
#pragma unroll
    for (int i = 0; i < 4; ++i) {
      int gm = m0 + m0w + mf * 16 + orow + i;
      if (gm >= M) continue;
      float rs = ROW_SCALE ? rowscale[gm] : 1.0f;
#pragma unroll
      for (int nf = 0; nf < 4; ++nf) {
        int gn = n0 + n0w + nf * 16 + lr;
        if (gn >= N) continue;
        float o = acc[mf][nf][i] * rs;
        if (ADD_BIAS) o += bias[gn];
        if constexpr (C_BF16) {
          ((unsigned short*)Cv)[(size_t)gm * N + gn] = f2bf(o);
        } else {
          ((float*)Cv)[(size_t)gm * N + gn] = o;
        }
      }
    }
  }
}

// ---------------- Aggregation: one wave per node, 4 bf16 channels per lane ----------------
// out[c] = bf16( relu(dinv[c] * (sum_{e: col=c} Hs[row_e] + Hs[c]) + bias) )
// Hs already carries the dinv[row] factor (fused into GEMM epilogue). fp32 accumulate.
// Indices loaded 64-per-wave coalesced, broadcast via shfl; gathers unrolled 8-deep
// so 8 independent 512B row-reads are in flight per wave (MLP, latency hiding).

__global__ __launch_bounds__(256) void k_agg_bias_relu(
    const ushort4* __restrict__ Hs, const int* __restrict__ csr_off,
    const int* __restrict__ csr_row, const float* __restrict__ dinv,
    const float* __restrict__ bias, ushort4* __restrict__ out, int n) {
  int node = blockIdx.x * 4 + (threadIdx.x >> 6);
  if (node >= n) return;
  int lane = threadIdx.x & 63;                 // HIDDEN/4 = 64 lanes x 4 channels
  ushort4 sv = Hs[(size_t)node * 64 + lane];   // self loop
  float ax = bf2f(sv.x), ay = bf2f(sv.y), az = bf2f(sv.z), aw = bf2f(sv.w);
  int beg = csr_off[node], end = csr_off[node + 1];
  for (int b = beg; b < end; b += 64) {
    int idx = (b + lane < end) ? csr_row[b + lane] : 0;  // coalesced 64-wide index load
    int cnt = min(end - b, 64);
    int j = 0;
    for (; j + 8 <= cnt; j += 8) {
      ushort4 v[8];
#pragma unroll
      for (int u = 0; u < 8; ++u) {
        int r = __shfl(idx, j + u);
        v[u] = Hs[(size_t)r * 64 + lane];
      }
#pragma unroll
      for (int u = 0; u < 8; ++u) {
        ax += bf2f(v[u].x); ay += bf2f(v[u].y);
        az += bf2f(v[u].z); aw += bf2f(v[u].w);
      }
    }
    for (; j < cnt; ++j) {
      int r = __shfl(idx, j);
      ushort4 v = Hs[(size_t)r * 64 + lane];
      ax += bf2f(v.x); ay += bf2f(v.y); az += bf2f(v.z); aw += bf2f(v.w);
    }
  }
  float di = dinv[node];
  float4 b4 = ((const float4*)bias)[lane];
  ushort4 o;
  o.x = f2bf(fmaxf(fmaf(ax, di, b4.x), 0.f));
  o.y = f2bf(fmaxf(fmaf(ay, di, b4.y), 0.f));
  o.z = f2bf(fmaxf(fmaf(az, di, b4.z), 0.f));
  o.w = f2bf(fmaxf(fmaf(aw, di, b4.w), 0.f));
  out[(size_t)node * 64 + lane] = o;
}

// ---------------- launch ----------------

extern "C" void kernel_launch(void* const* d_in, const int* in_sizes, int n_in,
                              void* d_out, int out_size, void* d_ws, size_t ws_size,
                              hipStream_t stream) {
  const float* x   = (const float*)d_in[0];
  const int*   ei  = (const int*)d_in[1];   // int32! (JAX x64 disabled; harness: integer -> int*)
  const float* W1  = (const float*)d_in[2];
  const float* b1  = (const float*)d_in[3];
  const float* W2  = (const float*)d_in[4];
  const float* b2  = (const float*)d_in[5];
  const float* Wfc = (const float*)d_in[6];
  const float* bfc = (const float*)d_in[7];
  float* out = (float*)d_out;

  const int* row = ei;             // sources
  const int* col = ei + N_EDGES;   // targets

  // Scratch carved from d_out (400 MB fp32; all regions dead before FC writes):
  //   bufA (pre-agg Hs, bf16, 51.2 MB) | csr_row (12.8 MB) | Xh (102.4) | Xl (102.4)
  //   | Bp1 (0.79 MB) | Bp2 (0.26 MB)
  char* q = (char*)d_out;
  unsigned short* bufA    = (unsigned short*)q;                        // [N*HIDDEN] bf16
  int*            csr_row = (int*)(q + 51200000);
  unsigned short* Xh      = (unsigned short*)(q + 64000000);           // [N][512] bf16
  unsigned short* Xl      = (unsigned short*)(q + 166400000);
  unsigned short* Bp1     = (unsigned short*)(q + 268800000);          // 3 segs x 64kb x 256 x 8
  unsigned short* Bp2     = (unsigned short*)(q + 269600000);          // 2 segs x 32kb x 256 x 8

  // d_ws: small CSR arrays + post-agg feature buffer + FC weights (must survive into FC)
  char* p = (char*)d_ws;
  auto alloc = [&](size_t bytes) { char* r = p; p += (bytes + 255) & ~(size_t)255; return r; };
  int*   cnt     = (int*)alloc(sizeof(int) * N_NODES);
  int*   csr_off = (int*)alloc(sizeof(int) * (N_NODES + 1));
  int*   cursor  = (int*)alloc(sizeof(int) * N_NODES);
  int*   blk     = (int*)alloc(sizeof(int) * 128);
  float* dinv    = (float*)alloc(sizeof(float) * N_NODES);
  unsigned short* bufB = (unsigned short*)alloc(sizeof(unsigned short) * (size_t)N_NODES * HIDDEN);
  unsigned short* BpFC = (unsigned short*)alloc(sizeof(unsigned short) * (size_t)2 * 32 * 1024 * 8); // 1 MB

  const int nscan = (N_NODES + SCAN_CHUNK - 1) / SCAN_CHUNK;  // 98 (<=128)

  // input prep (independent of CSR chain)
  hipLaunchKernelGGL(k_split_x, dim3(2048), dim3(256), 0, stream,
                     (const float4*)x, (ushort4*)Xh, (ushort4*)Xl, N_NODES * IN_DIM / 4);
  // W1: segs [hi | lo | hi], 64 kb-rows per seg, Npad=256
  hipLaunchKernelGGL(k_prep_w, dim3((64 * 256 + 255) / 256), dim3(256), 0, stream,
                     W1, IN_DIM, HIDDEN, HIDDEN, Bp1, Bp1 + (size_t)64 * 256 * 8,
                     Bp1 + (size_t)2 * 64 * 256 * 8);
  // W2: segs [hi | lo], 32 kb-rows per seg
  hipLaunchKernelGGL(k_prep_w, dim3((32 * 256 + 255) / 256), dim3(256), 0, stream,
                     W2, HIDDEN, HIDDEN, HIDDEN, Bp2, Bp2 + (size_t)32 * 256 * 8,
                     (unsigned short*)nullptr);
  // Wfc: segs [hi | lo], Npad=1024
  hipLaunchKernelGGL(k_prep_w, dim3((32 * 1024 + 255) / 256), dim3(256), 0, stream,
                     Wfc, HIDDEN, NUM_CLASSES, 1024, BpFC, BpFC + (size_t)32 * 1024 * 8,
                     (unsigned short*)nullptr);

  // CSR build
  hipLaunchKernelGGL(k_zero_cnt, dim3((N_NODES + 255) / 256), dim3(256), 0, stream, cnt, N_NODES);
  hipLaunchKernelGGL(k_hist, dim3((N_EDGES + 255) / 256), dim3(256), 0, stream, col, cnt, N_EDGES);
  hipLaunchKernelGGL(k_scan_block_sums, dim3(nscan), dim3(256), 0, stream, cnt, blk, N_NODES);
  hipLaunchKernelGGL(k_scan_tops, dim3(1), dim3(128), 0, stream, blk, nscan, csr_off + N_NODES);
  hipLaunchKernelGGL(k_scan_final, dim3(nscan), dim3(256), 0, stream, cnt, blk, csr_off, cursor, dinv, N_NODES);
  hipLaunchKernelGGL(k_fill, dim3((N_EDGES + 255) / 256), dim3(256), 0, stream, row, col, cursor, csr_row, N_EDGES);

  const int MB = (N_NODES + 127) / 128;  // 782

  // Layer 1: Hs = bf16((x @ W1) * dinv[row])
  // x@W1 = Xh@W1h + Xh@W1l + Xl@W1h; Xh staged once for its two B segs.
  hipLaunchKernelGGL((k_mfma_gemm<true, true, false>), dim3(HIDDEN / 128, MB), dim3(256), 0, stream,
                     Xh, 2, Xl, 1, Bp1, dinv, (const float*)nullptr, bufA,
                     N_NODES, HIDDEN, HIDDEN, IN_DIM);
  hipLaunchKernelGGL(k_agg_bias_relu, dim3((N_NODES + 3) / 4), dim3(256), 0, stream,
                     (const ushort4*)bufA, csr_off, csr_row, dinv, b1, (ushort4*)bufB, N_NODES);

  // Layer 2: A (bufB) is exact bf16, staged once; B split hi+lo
  hipLaunchKernelGGL((k_mfma_gemm<true, true, false>), dim3(HIDDEN / 128, MB), dim3(256), 0, stream,
                     bufB, 2, (const unsigned short*)nullptr, 0, Bp2, dinv, (const float*)nullptr, bufA,
                     N_NODES, HIDDEN, HIDDEN, HIDDEN);
  hipLaunchKernelGGL(k_agg_bias_relu, dim3((N_NODES + 3) / 4), dim3(256), 0, stream,
                     (const ushort4*)bufA, csr_off, csr_row, dinv, b2, (ushort4*)bufB, N_NODES);

  // FC: out = bufB @ Wfc + bfc (fp32 out over the whole d_out; scratch regions dead by now)
  hipLaunchKernelGGL((k_mfma_gemm<false, false, true>), dim3(1024 / 128, MB), dim3(256), 0, stream,
                     bufB, 2, (const unsigned short*)nullptr, 0, BpFC, (const float*)nullptr, bfc, out,
                     N_NODES, NUM_CLASSES, 1024, HIDDEN);
}